// Round 6
// baseline (308.646 us; speedup 1.0000x reference)
//
#include <hip/hip_runtime.h>
#include <math.h>

#define O_  32
#define I_  32
#define K_  13
#define N_  4096
#define IK  (I_ * K_)     // 416
#define OIK (O_ * IK)     // 13312

typedef float f32x4 __attribute__((ext_vector_type(4)));

// Round 6: NB=1, one n per block, grid 4096.
// Theory: with NB=4 (1024 blocks = exactly one residency pass) every block
// machine-wide does its latency-bound gather at t=0 with nothing to overlap.
// With 4096 blocks, block turnover pipelines gathers under other blocks'
// mask streams automatically; only the first ~4 blocks/CU expose a (4x
// smaller, 2-level) gather. Also: fewer live VGPRs than R1 (no nl loop),
// no register prefetch (R3/R5 postmortem: that was the poison), LDS 1.7KB.
__global__ __launch_bounds__(256, 4) void plaq_kernel(
    const float* __restrict__ x,      // (I, N)
    const float* __restrict__ W,      // (O, I, K)
    const float* __restrict__ b,      // (O,)
    const float* __restrict__ mask,   // (N, O, I, K)
    const int*   __restrict__ shifts, // (N, K)
    float* __restrict__ out)          // (O, N)
{
    __shared__ __align__(16) float g_lds[IK];
    const int n   = blockIdx.x;
    const int tid = threadIdx.x;
    const int o   = tid >> 3;
    const int s8  = tid & 7;

    // ---- Gather: 416 elems, 256 threads, 2 clamped slots, 2 latency levels.
    {
        const int idx0 = tid;                          // always < 416
        const int idx1 = tid + 256;                    // valid if < 416
        const int v1   = (idx1 < IK);
        const int i0 = idx0 / K_, k0 = idx0 - i0 * K_;
        const int j1 = v1 ? idx1 : 0;
        const int i1 = j1 / K_,  k1 = j1 - i1 * K_;
        // level 1: both shift loads, independent
        const int s0 = shifts[n * K_ + k0];
        const int s1 = shifts[n * K_ + k1];
        // level 2: both x loads, independent
        const float x0 = x[i0 * N_ + s0];
        const float x1 = x[i1 * N_ + s1];
        g_lds[idx0] = x0;
        if (v1) g_lds[idx1] = x1;
    }

    // W into registers while the gather is in flight (independent).
    const f32x4* w4 = (const f32x4*)(W + o * IK);
    f32x4 w[13];
#pragma unroll
    for (int m = 0; m < 13; ++m) w[m] = w4[s8 + 8 * m];
    const float bo = b[o];

    __syncthreads();

    const float scale = (float)((2.0 + 2.0 * M_E) / (M_E - 1.0));

    const f32x4* m4 = (const f32x4*)(mask + (size_t)n * OIK + o * IK);
    const f32x4* g4 = (const f32x4*)(&g_lds[0]);

    float a0 = 0.f, a1 = 0.f, a2 = 0.f, a3 = 0.f;
#pragma unroll
    for (int m = 0; m < 13; ++m) {
        f32x4 mv = m4[s8 + 8 * m];          // plain load: allow L3 allocate
        f32x4 wg = w[m] * g4[s8 + 8 * m];
        a0 = fmaf(mv.x, wg.x, a0);
        a1 = fmaf(mv.y, wg.y, a1);
        a2 = fmaf(mv.z, wg.z, a2);
        a3 = fmaf(mv.w, wg.w, a3);
    }
    float acc = (a0 + a1) + (a2 + a3);

    // Reduce across the 8 lanes sharing this o (within one wave).
    acc += __shfl_down(acc, 4);
    acc += __shfl_down(acc, 2);
    acc += __shfl_down(acc, 1);

    if (s8 == 0) {
        float y  = acc + bo;
        float sg = 1.0f / (1.0f + __expf(-y));
        out[o * N_ + n] = (sg - 0.5f) * scale;
    }
}

extern "C" void kernel_launch(void* const* d_in, const int* in_sizes, int n_in,
                              void* d_out, int out_size, void* d_ws, size_t ws_size,
                              hipStream_t stream) {
    const float* x      = (const float*)d_in[0];
    const float* Wconv  = (const float*)d_in[1];
    const float* bconv  = (const float*)d_in[2];
    const float* mask   = (const float*)d_in[3];
    const int*   shifts = (const int*)d_in[4];
    float* out = (float*)d_out;

    plaq_kernel<<<N_, 256, 0, stream>>>(x, Wconv, bconv, mask, shifts, out);
}